// Round 1
// baseline (787.590 us; speedup 1.0000x reference)
//
#include <hip/hip_runtime.h>

// GATv2 fused kernel for MI355X (gfx950).
// B=1, N=1024, D=128, OUT=MID=128, H=8, HS=MH=16.
//
// Plan:
//  k_lin  : z = [node|hidden] (1024x256); values/skip/pre1/pre2 = z@W + b  (fp32, exact)
//  k_preg : pre_g = graph @ Wg + bg  (128)
//  k_attn : one block per destination row i. Flash-style online softmax over
//           j-tiles of 16. pre_att tile computed by mfma_f32_16x16x32_bf16
//           (edge tile bf16 in LDS x We column fragments in regs), with the
//           accumulator INITIALIZED to pre1[j,m] + pre2[i,m] + pre_g[m] + be[m].
//           Logit = rowwise <leaky_relu(pre_att), A[h]> via DPP row_ror
//           all-reduce (no DS-pipe traffic). Output accumulated online,
//           final: relu(attn/S + skip).

#define NN 1024
#define DD 128

typedef __bf16 bf16x8 __attribute__((ext_vector_type(8)));
typedef float  f32x4  __attribute__((ext_vector_type(4)));

template<int C>
__device__ __forceinline__ float dpp_add(float x) {
  int y = __builtin_amdgcn_update_dpp(0, __builtin_bit_cast(int, x), C, 0xF, 0xF, false);
  return x + __builtin_bit_cast(float, y);
}

// all-reduce sum over the 16 lanes of a DPP row (rotate-butterfly: ror 1,2,4,8)
__device__ __forceinline__ float allred16(float x) {
  x = dpp_add<0x121>(x);   // row_ror:1
  x = dpp_add<0x122>(x);   // row_ror:2
  x = dpp_add<0x124>(x);   // row_ror:4
  x = dpp_add<0x128>(x);   // row_ror:8
  return x;
}

__device__ __forceinline__ float rdlane(float x, int l) {
  return __builtin_bit_cast(float, __builtin_amdgcn_readlane(__builtin_bit_cast(int, x), l));
}

// ---------------- kernel 1: z-linears ----------------
// grid (64 row-tiles, 4 mats), block 256. Each block: 16 rows x 128 cols, one W.
__global__ __launch_bounds__(256)
void k_lin(const float* __restrict__ node, const float* __restrict__ hidden,
           const float* __restrict__ Wm, const float* __restrict__ bm,
           const float* __restrict__ Wskip, const float* __restrict__ bskip,
           const float* __restrict__ W1, const float* __restrict__ b1,
           const float* __restrict__ W2, const float* __restrict__ b2,
           float* __restrict__ outv, float* __restrict__ outskip,
           float* __restrict__ out1, float* __restrict__ out2)
{
  __shared__ float zt[16][256];
  const int rt = blockIdx.x;
  const int mat = blockIdx.y;
  const int tid = threadIdx.x;
  const float* W; const float* bias; float* out;
  if (mat == 0)      { W = Wm;    bias = bm;    out = outv;    }
  else if (mat == 1) { W = Wskip; bias = bskip; out = outskip; }
  else if (mat == 2) { W = W1;    bias = b1;    out = out1;    }
  else               { W = W2;    bias = b2;    out = out2;    }

  {
    const int r = tid >> 4, c = (tid & 15) * 8;
    const float4* np_ = (const float4*)(node + (rt*16 + r)*128 + c);
    *(float4*)&zt[r][c]       = np_[0];
    *(float4*)&zt[r][c+4]     = np_[1];
    const float4* hp = (const float4*)(hidden + (rt*16 + r)*128 + c);
    *(float4*)&zt[r][128+c]   = hp[0];
    *(float4*)&zt[r][128+c+4] = hp[1];
  }
  __syncthreads();

  const int c = tid & 127, rh = (tid >> 7) * 8;
  float acc[8];
  const float bv = bias[c];
  for (int r = 0; r < 8; ++r) acc[r] = bv;
  for (int k = 0; k < 256; ++k) {
    float w = W[k*128 + c];                    // coalesced across lanes
    for (int r = 0; r < 8; ++r) acc[r] = fmaf(zt[rh + r][k], w, acc[r]);  // LDS broadcast
  }
  for (int r = 0; r < 8; ++r) out[(rt*16 + rh + r)*128 + c] = acc[r];
}

// ---------------- kernel: pre_g ----------------
__global__ void k_preg(const float* __restrict__ g, const float* __restrict__ Wg,
                       const float* __restrict__ bg, float* __restrict__ outg)
{
  const int c = threadIdx.x;  // 128
  float acc = bg[c];
  for (int k = 0; k < 128; ++k) acc = fmaf(g[k], Wg[k*128 + c], acc);
  outg[c] = acc;
}

// ---------------- kernel 2: fused attention ----------------
// grid 1024 (one block per i), block 256 = 4 waves, each wave owns 2 heads.
__global__ __launch_bounds__(256, 4)
void k_attn(const float* __restrict__ edge, const int* __restrict__ adj,
            const float* __restrict__ We, const float* __restrict__ be,
            const float* __restrict__ pre1, const float* __restrict__ pre2,
            const float* __restrict__ preg, const float* __restrict__ values,
            const float* __restrict__ skipv, const float* __restrict__ A,
            const float* __restrict__ Ab, float* __restrict__ out)
{
  constexpr int SR = 136;                       // LDS row stride in bf16 (272 B: 16B-aligned, conflict-benign)
  __shared__ __align__(16) __bf16 et[16 * SR];  // 16 j-rows x 128 k
  __shared__ __align__(16) int adjt[16];

  const int i   = blockIdx.x;
  const int tid = threadIdx.x;
  const int lane = tid & 63;
  const int wv  = tid >> 6;          // wave 0..3
  const int q   = lane >> 4;         // DPP row / quad group
  const int ml  = lane & 15;
  const int h0 = wv*2, h1 = wv*2 + 1;
  const int m0 = h0*16 + ml, m1 = m0 + 16;

  // B fragments: We[k][m] column slices, bf16, kept in regs (We is L2-hot).
  bf16x8 b0[4], b1[4];
  for (int ks = 0; ks < 4; ++ks)
    for (int kk = 0; kk < 8; ++kk) {
      int k = ks*32 + q*8 + kk;
      b0[ks][kk] = (__bf16)We[k*DD + m0];
      b1[ks][kk] = (__bf16)We[k*DD + m1];
    }

  const float c20 = pre2[i*DD + m0] + preg[m0] + be[m0];
  const float c21 = pre2[i*DD + m1] + preg[m1] + be[m1];
  const float aw0 = A[h0*16 + ml], aw1 = A[h1*16 + ml];
  const float ab0 = Ab[h0],        ab1 = Ab[h1];

  float M0 = -1e30f, S0 = 0.f, o0 = 0.f;
  float M1 = -1e30f, S1 = 0.f, o1 = 0.f;

  const float* erow = edge + (size_t)i * (NN * DD);
  const int sr = tid >> 4, sc = (tid & 15) * 8;   // staging: row 0..15, col 0..120

  // register prefetch of tile 0
  float4 pv0, pv1; int padj = 0;
  {
    const float4* s = (const float4*)(erow + sr*DD + sc);
    pv0 = s[0]; pv1 = s[1];
  }
  if (tid < 16) padj = adj[i*NN + tid];

  for (int jt = 0; jt < 64; ++jt) {
    __syncthreads();                               // WAR: previous compute done
    {
      bf16x8 w;
      w[0]=(__bf16)pv0.x; w[1]=(__bf16)pv0.y; w[2]=(__bf16)pv0.z; w[3]=(__bf16)pv0.w;
      w[4]=(__bf16)pv1.x; w[5]=(__bf16)pv1.y; w[6]=(__bf16)pv1.z; w[7]=(__bf16)pv1.w;
      *(bf16x8*)&et[sr*SR + sc] = w;
      if (tid < 16) adjt[tid] = padj;
    }
    __syncthreads();
    if (jt < 63) {                                 // prefetch next tile: latency hidden behind compute
      const float4* s = (const float4*)(erow + ((jt+1)*16 + sr)*DD + sc);
      pv0 = s[0]; pv1 = s[1];
      if (tid < 16) padj = adj[i*NN + (jt+1)*16 + tid];
    }

    const int j0 = jt*16 + q*4;
    // acc init = pre1[j,m] + (pre2[i,m] + pre_g[m] + be[m]) — C/D layout: row=4q+r, col=ml
    f32x4 acc0, acc1;
    for (int r = 0; r < 4; ++r) {
      acc0[r] = pre1[(j0+r)*DD + m0] + c20;
      acc1[r] = pre1[(j0+r)*DD + m1] + c21;
    }
    for (int ks = 0; ks < 4; ++ks) {
      // A-frag: A[m=ml][k=q*8+kk] → LDS row ml, contiguous 16 B
      bf16x8 a = *(const bf16x8*)&et[ml*SR + ks*32 + q*8];
      acc0 = __builtin_amdgcn_mfma_f32_16x16x32_bf16(a, b0[ks], acc0, 0, 0, 0);
      acc1 = __builtin_amdgcn_mfma_f32_16x16x32_bf16(a, b1[ks], acc1, 0, 0, 0);
    }

    // leaky_relu + per-head weight, then 16-lane all-reduce over m (DPP, no DS)
    float t0[4], t1[4];
    for (int r = 0; r < 4; ++r) {
      float x0 = acc0[r]; x0 = (x0 > 0.f) ? x0 : 0.01f*x0; t0[r] = x0*aw0;
      float x1 = acc1[r]; x1 = (x1 > 0.f) ? x1 : 0.01f*x1; t1[r] = x1*aw1;
    }
    for (int r = 0; r < 4; ++r) { t0[r] = allred16(t0[r]); t1[r] = allred16(t1[r]); }

    const int4 av = *(const int4*)&adjt[q*4];      // adj for this row group's 4 j's (broadcast)
    const int aarr[4] = {av.x, av.y, av.z, av.w};
    float tm0 = -3.0e38f, tm1 = -3.0e38f;
    for (int r = 0; r < 4; ++r) {
      t0[r] = aarr[r] ? (t0[r] + ab0) : -3.0e38f;  // masked → exp underflows to 0
      t1[r] = aarr[r] ? (t1[r] + ab1) : -3.0e38f;
      tm0 = fmaxf(tm0, t0[r]); tm1 = fmaxf(tm1, t1[r]);
    }
    // cross-row max (values row-uniform): readlane, no DS
    float g0 = fmaxf(fmaxf(rdlane(tm0,0), rdlane(tm0,16)), fmaxf(rdlane(tm0,32), rdlane(tm0,48)));
    float g1 = fmaxf(fmaxf(rdlane(tm1,0), rdlane(tm1,16)), fmaxf(rdlane(tm1,32), rdlane(tm1,48)));
    float Mn0 = fmaxf(M0, g0), Mn1 = fmaxf(M1, g1);
    float al0 = __expf(M0 - Mn0), al1 = __expf(M1 - Mn1);
    M0 = Mn0; M1 = Mn1;

    float p0[4], p1[4], sp0 = 0.f, sp1 = 0.f;
    for (int r = 0; r < 4; ++r) {
      p0[r] = __expf(t0[r] - Mn0); sp0 += p0[r];
      p1[r] = __expf(t1[r] - Mn1); sp1 += p1[r];
    }
    float Ss0 = rdlane(sp0,0)+rdlane(sp0,16)+rdlane(sp0,32)+rdlane(sp0,48);
    float Ss1 = rdlane(sp1,0)+rdlane(sp1,16)+rdlane(sp1,32)+rdlane(sp1,48);
    S0 = S0*al0 + Ss0; S1 = S1*al1 + Ss1;

    float va0 = 0.f, va1 = 0.f;
    for (int r = 0; r < 4; ++r) {
      va0 = fmaf(p0[r], values[(j0+r)*DD + m0], va0);
      va1 = fmaf(p1[r], values[(j0+r)*DD + m1], va1);
    }
    o0 = o0*al0 + va0; o1 = o1*al1 + va1;
  }

  // combine the 4 row-groups' j-partials
  o0 += __shfl_xor(o0, 16); o0 += __shfl_xor(o0, 32);
  o1 += __shfl_xor(o1, 16); o1 += __shfl_xor(o1, 32);
  if (q == 0) {
    float r0 = o0 / S0 + skipv[i*DD + m0];
    float r1 = o1 / S1 + skipv[i*DD + m1];
    out[i*DD + m0] = fmaxf(r0, 0.f);
    out[i*DD + m1] = fmaxf(r1, 0.f);
  }
}

extern "C" void kernel_launch(void* const* d_in, const int* in_sizes, int n_in,
                              void* d_out, int out_size, void* d_ws, size_t ws_size,
                              hipStream_t stream)
{
  const float* node   = (const float*)d_in[0];
  const float* edge   = (const float*)d_in[1];
  const float* graph  = (const float*)d_in[2];
  const int*   adj    = (const int*)d_in[3];
  const float* hidden = (const float*)d_in[4];
  const float* Wm     = (const float*)d_in[5];
  const float* bm     = (const float*)d_in[6];
  const float* Wskip  = (const float*)d_in[7];
  const float* bskip  = (const float*)d_in[8];
  const float* W1     = (const float*)d_in[9];
  const float* b1     = (const float*)d_in[10];
  const float* W2     = (const float*)d_in[11];
  const float* b2     = (const float*)d_in[12];
  const float* We     = (const float*)d_in[13];
  const float* be     = (const float*)d_in[14];
  const float* Wg     = (const float*)d_in[15];
  const float* bg     = (const float*)d_in[16];
  const float* A      = (const float*)d_in[17];
  const float* Ab     = (const float*)d_in[18];
  float* out = (float*)d_out;

  float* ws     = (float*)d_ws;          // ~2.0 MB used
  float* values = ws;                    // 1024x128
  float* pre1   = ws + 131072;
  float* pre2   = ws + 262144;
  float* skipv  = ws + 393216;
  float* preg   = ws + 524288;           // 128

  hipLaunchKernelGGL(k_lin, dim3(64, 4), dim3(256), 0, stream,
                     node, hidden, Wm, bm, Wskip, bskip, W1, b1, W2, b2,
                     values, skipv, pre1, pre2);
  hipLaunchKernelGGL(k_preg, dim3(1), dim3(128), 0, stream, graph, Wg, bg, preg);
  hipLaunchKernelGGL(k_attn, dim3(1024), dim3(256), 0, stream,
                     edge, adj, We, be, pre1, pre2, preg, values, skipv, A, Ab, out);
}

// Round 2
// 775.243 us; speedup vs baseline: 1.0159x; 1.0159x over previous
//
#include <hip/hip_runtime.h>

// GATv2 fused kernel for MI355X (gfx950).
// B=1, N=1024, D=128, OUT=MID=128, H=8, HS=MH=16.
//
//  k_lin  : z = [node|hidden] (1024x256); values/skip/pre1/pre2 = z@W + b (fp32)
//           + pre_g folded in (one block's tail).
//  k_attn : one block per destination row i. j-tiles of 16, DOUBLE-BUFFERED
//           LDS (1 barrier/iter) + register prefetch 2 tiles ahead.
//           pre_att tile = mfma_f32_16x16x32_bf16(edge_bf16, We_bf16) with
//           accumulator initialized to pre1[j]+pre2[i]+pre_g+be.
//           Logit = <leaky_relu(pre_att), A[h]> via DPP row_ror all-reduce.
//           Softmax WITHOUT max subtraction (logits |x| <~ 10, exp safe in
//           fp32; masked -> exp(-1e30)=0). Final: relu(o/S + skip).

#define NN 1024
#define DD 128

typedef __bf16 bf16x8 __attribute__((ext_vector_type(8)));
typedef float  f32x4  __attribute__((ext_vector_type(4)));

template<int C>
__device__ __forceinline__ float dpp_add(float x) {
  int y = __builtin_amdgcn_update_dpp(0, __builtin_bit_cast(int, x), C, 0xF, 0xF, false);
  return x + __builtin_bit_cast(float, y);
}
// all-reduce sum over the 16 lanes of a DPP row (row_ror 1,2,4,8)
__device__ __forceinline__ float allred16(float x) {
  x = dpp_add<0x121>(x);
  x = dpp_add<0x122>(x);
  x = dpp_add<0x124>(x);
  x = dpp_add<0x128>(x);
  return x;
}
__device__ __forceinline__ float rdlane(float x, int l) {
  return __builtin_bit_cast(float, __builtin_amdgcn_readlane(__builtin_bit_cast(int, x), l));
}

// ---------------- kernel 1: z-linears (+ pre_g tail) ----------------
__global__ __launch_bounds__(256)
void k_lin(const float* __restrict__ node, const float* __restrict__ hidden,
           const float* __restrict__ Wm, const float* __restrict__ bm,
           const float* __restrict__ Wskip, const float* __restrict__ bskip,
           const float* __restrict__ W1, const float* __restrict__ b1,
           const float* __restrict__ W2, const float* __restrict__ b2,
           const float* __restrict__ g, const float* __restrict__ Wg,
           const float* __restrict__ bg,
           float* __restrict__ outv, float* __restrict__ outskip,
           float* __restrict__ out1, float* __restrict__ out2,
           float* __restrict__ outg)
{
  __shared__ float zt[16][256];
  const int rt = blockIdx.x;
  const int mat = blockIdx.y;
  const int tid = threadIdx.x;
  const float* W; const float* bias; float* out;
  if (mat == 0)      { W = Wm;    bias = bm;    out = outv;    }
  else if (mat == 1) { W = Wskip; bias = bskip; out = outskip; }
  else if (mat == 2) { W = W1;    bias = b1;    out = out1;    }
  else               { W = W2;    bias = b2;    out = out2;    }

  {
    const int r = tid >> 4, c = (tid & 15) * 8;
    const float4* np_ = (const float4*)(node + (rt*16 + r)*128 + c);
    *(float4*)&zt[r][c]       = np_[0];
    *(float4*)&zt[r][c+4]     = np_[1];
    const float4* hp = (const float4*)(hidden + (rt*16 + r)*128 + c);
    *(float4*)&zt[r][128+c]   = hp[0];
    *(float4*)&zt[r][128+c+4] = hp[1];
  }
  __syncthreads();

  const int c = tid & 127, rh = (tid >> 7) * 8;
  float acc[8];
  const float bv = bias[c];
  for (int r = 0; r < 8; ++r) acc[r] = bv;
  for (int k = 0; k < 256; ++k) {
    float w = W[k*128 + c];                    // coalesced across lanes
    for (int r = 0; r < 8; ++r) acc[r] = fmaf(zt[rh + r][k], w, acc[r]);  // LDS broadcast
  }
  for (int r = 0; r < 8; ++r) out[(rt*16 + rh + r)*128 + c] = acc[r];

  // pre_g, folded into one block
  if (mat == 3 && rt == 0 && tid < 128) {
    float a = bg[tid];
    for (int k = 0; k < 128; ++k) a = fmaf(g[k], Wg[k*128 + tid], a);
    outg[tid] = a;
  }
}

// ---------------- kernel 2: fused attention ----------------
// grid 1024 (one block per i), block 256 = 4 waves, each wave owns 2 heads.
__global__ __launch_bounds__(256, 4)
void k_attn(const float* __restrict__ edge, const int* __restrict__ adj,
            const float* __restrict__ We, const float* __restrict__ be,
            const float* __restrict__ pre1, const float* __restrict__ pre2,
            const float* __restrict__ preg, const float* __restrict__ values,
            const float* __restrict__ skipv, const float* __restrict__ A,
            const float* __restrict__ Ab, float* __restrict__ out)
{
  constexpr int SR = 136;                          // LDS row stride (272 B)
  __shared__ __align__(16) __bf16 et[2][16 * SR];  // double-buffered 16x128 tile
  __shared__ __align__(16) int adjt[2][16];

  const int i   = blockIdx.x;
  const int tid = threadIdx.x;
  const int lane = tid & 63;
  const int wv  = tid >> 6;          // wave 0..3
  const int q   = lane >> 4;         // DPP row / quad group
  const int ml  = lane & 15;
  const int h0 = wv*2, h1 = wv*2 + 1;
  const int m0 = h0*16 + ml, m1 = m0 + 16;

  // B fragments: We[k][m] column slices, bf16, in regs (We is L2-hot, 64 KB)
  bf16x8 b0[4], b1[4];
  for (int ks = 0; ks < 4; ++ks)
    for (int kk = 0; kk < 8; ++kk) {
      int k = ks*32 + q*8 + kk;
      b0[ks][kk] = (__bf16)We[k*DD + m0];
      b1[ks][kk] = (__bf16)We[k*DD + m1];
    }

  const float c20 = pre2[i*DD + m0] + preg[m0] + be[m0];
  const float c21 = pre2[i*DD + m1] + preg[m1] + be[m1];
  const float aw0 = A[h0*16 + ml], aw1 = A[h1*16 + ml];
  const float ab0 = Ab[h0],        ab1 = Ab[h1];

  float S0 = 0.f, o0 = 0.f;          // no-max softmax accumulators
  float S1 = 0.f, o1 = 0.f;

  const float* erow = edge + (size_t)i * (NN * DD);
  const int sr = tid >> 4, sc = (tid & 15) * 8;   // staging: row 0..15, col*8

  // prologue: tile0 -> LDS buf0; tile1 -> regs
  float4 pv0, pv1; int padj = 0;
  {
    const float4* s = (const float4*)(erow + sr*DD + sc);
    pv0 = s[0]; pv1 = s[1];
  }
  if (tid < 16) padj = adj[i*NN + tid];
  {
    bf16x8 w;
    w[0]=(__bf16)pv0.x; w[1]=(__bf16)pv0.y; w[2]=(__bf16)pv0.z; w[3]=(__bf16)pv0.w;
    w[4]=(__bf16)pv1.x; w[5]=(__bf16)pv1.y; w[6]=(__bf16)pv1.z; w[7]=(__bf16)pv1.w;
    *(bf16x8*)&et[0][sr*SR + sc] = w;
    if (tid < 16) adjt[0][tid] = padj;
  }
  {
    const float4* s = (const float4*)(erow + (16 + sr)*DD + sc);
    pv0 = s[0]; pv1 = s[1];
  }
  if (tid < 16) padj = adj[i*NN + 16 + tid];
  __syncthreads();

  for (int jt = 0; jt < 64; ++jt) {
    const int cur = jt & 1, nxt = cur ^ 1;
    // publish tile jt+1 (regs -> LDS buf nxt); reads this iter touch buf cur only
    if (jt < 63) {
      bf16x8 w;
      w[0]=(__bf16)pv0.x; w[1]=(__bf16)pv0.y; w[2]=(__bf16)pv0.z; w[3]=(__bf16)pv0.w;
      w[4]=(__bf16)pv1.x; w[5]=(__bf16)pv1.y; w[6]=(__bf16)pv1.z; w[7]=(__bf16)pv1.w;
      *(bf16x8*)&et[nxt][sr*SR + sc] = w;
      if (tid < 16) adjt[nxt][tid] = padj;
    }
    // prefetch tile jt+2 two stages ahead (in flight during this whole iter)
    if (jt < 62) {
      const float4* s = (const float4*)(erow + ((jt+2)*16 + sr)*DD + sc);
      pv0 = s[0]; pv1 = s[1];
      if (tid < 16) padj = adj[i*NN + (jt+2)*16 + tid];
    }

    const int j0 = jt*16 + q*4;
    // acc init = pre1[j,m] + (pre2[i,m] + pre_g[m] + be[m]); C/D: row=4q+r, col=ml
    f32x4 acc0, acc1;
    for (int r = 0; r < 4; ++r) {
      acc0[r] = pre1[(j0+r)*DD + m0] + c20;
      acc1[r] = pre1[(j0+r)*DD + m1] + c21;
    }
    for (int ks = 0; ks < 4; ++ks) {
      bf16x8 a = *(const bf16x8*)&et[cur][ml*SR + ks*32 + q*8];
      acc0 = __builtin_amdgcn_mfma_f32_16x16x32_bf16(a, b0[ks], acc0, 0, 0, 0);
      acc1 = __builtin_amdgcn_mfma_f32_16x16x32_bf16(a, b1[ks], acc1, 0, 0, 0);
    }

    // leaky_relu, per-head weight, 16-lane all-reduce over m (DPP, no DS)
    float t0[4], t1[4];
    for (int r = 0; r < 4; ++r) {
      float x0 = acc0[r]; x0 = (x0 > 0.f) ? x0 : 0.01f*x0; t0[r] = x0*aw0;
      float x1 = acc1[r]; x1 = (x1 > 0.f) ? x1 : 0.01f*x1; t1[r] = x1*aw1;
    }
    for (int r = 0; r < 4; ++r) { t0[r] = allred16(t0[r]); t1[r] = allred16(t1[r]); }

    const int4 av = *(const int4*)&adjt[cur][q*4];
    const int aarr[4] = {av.x, av.y, av.z, av.w};
    float p0[4], p1[4];
    for (int r = 0; r < 4; ++r) {
      float u0 = aarr[r] ? (t0[r] + ab0) : -1e30f;   // masked -> exp underflows to 0
      float u1 = aarr[r] ? (t1[r] + ab1) : -1e30f;
      p0[r] = __expf(u0); S0 += p0[r];
      p1[r] = __expf(u1); S1 += p1[r];
    }
    float va0 = 0.f, va1 = 0.f;
    for (int r = 0; r < 4; ++r) {
      va0 = fmaf(p0[r], values[(j0+r)*DD + m0], va0);
      va1 = fmaf(p1[r], values[(j0+r)*DD + m1], va1);
    }
    o0 += va0; o1 += va1;

    __syncthreads();   // one barrier/iter: orders reads(cur) vs next iter's write(cur)
  }

  // combine the 4 row-groups' j-partials
  o0 += __shfl_xor(o0, 16); o0 += __shfl_xor(o0, 32);
  o1 += __shfl_xor(o1, 16); o1 += __shfl_xor(o1, 32);
  const float St0 = rdlane(S0,0) + rdlane(S0,16) + rdlane(S0,32) + rdlane(S0,48);
  const float St1 = rdlane(S1,0) + rdlane(S1,16) + rdlane(S1,32) + rdlane(S1,48);
  if (q == 0) {
    float r0 = o0 / St0 + skipv[i*DD + m0];
    float r1 = o1 / St1 + skipv[i*DD + m1];
    out[i*DD + m0] = fmaxf(r0, 0.f);
    out[i*DD + m1] = fmaxf(r1, 0.f);
  }
}

extern "C" void kernel_launch(void* const* d_in, const int* in_sizes, int n_in,
                              void* d_out, int out_size, void* d_ws, size_t ws_size,
                              hipStream_t stream)
{
  const float* node   = (const float*)d_in[0];
  const float* edge   = (const float*)d_in[1];
  const float* graph  = (const float*)d_in[2];
  const int*   adj    = (const int*)d_in[3];
  const float* hidden = (const float*)d_in[4];
  const float* Wm     = (const float*)d_in[5];
  const float* bm     = (const float*)d_in[6];
  const float* Wskip  = (const float*)d_in[7];
  const float* bskip  = (const float*)d_in[8];
  const float* W1     = (const float*)d_in[9];
  const float* b1     = (const float*)d_in[10];
  const float* W2     = (const float*)d_in[11];
  const float* b2     = (const float*)d_in[12];
  const float* We     = (const float*)d_in[13];
  const float* be     = (const float*)d_in[14];
  const float* Wg     = (const float*)d_in[15];
  const float* bg     = (const float*)d_in[16];
  const float* A      = (const float*)d_in[17];
  const float* Ab     = (const float*)d_in[18];
  float* out = (float*)d_out;

  float* ws     = (float*)d_ws;          // ~2.0 MB used
  float* values = ws;                    // 1024x128
  float* pre1   = ws + 131072;
  float* pre2   = ws + 262144;
  float* skipv  = ws + 393216;
  float* preg   = ws + 524288;           // 128

  hipLaunchKernelGGL(k_lin, dim3(64, 4), dim3(256), 0, stream,
                     node, hidden, Wm, bm, Wskip, bskip, W1, b1, W2, b2,
                     graph, Wg, bg,
                     values, skipv, pre1, pre2, preg);
  hipLaunchKernelGGL(k_attn, dim3(1024), dim3(256), 0, stream,
                     edge, adj, We, be, pre1, pre2, preg, values, skipv, A, Ab, out);
}